// Round 2
// baseline (1025.062 us; speedup 1.0000x reference)
//
#include <hip/hip_runtime.h>
#include <hip/hip_cooperative_groups.h>

#define DD 192

namespace cg = cooperative_groups;

// All weight matrices consumed by stage3 are stored TRANSPOSED: WT[j*192+i] = W[i][j].
// hyper writes WtT/WcT/WmoeT directly; W_in/pm_W/out_W transposed once in-kernel.

struct KParams {
    const float *x, *W_in, *b_in, *feat_W, *feat_b, *feat_AW, *feat_Ab, *an_g, *an_b;
    const float *tm_W, *tm_b, *tm_AW, *tm_Ab, *tn_g, *tn_b;
    const float *cm_W, *cm_b, *cm_AW, *cm_Ab, *cn_g, *cn_b;
    const float *pm_W, *pm_b, *gate_W, *gate_b;
    const float *ex_W, *ex_b, *ex_AW, *ex_Ab, *mn_g, *mn_b, *out_W, *out_b;
    float *B0, *B1, *xm_sum, *a_pre, *WmoeT, *WtT, *WcT, *st1, *st2, *st3;
    float *a0, *gate, *b_moe, *WinT, *pmT, *outT, *out;
};

struct Smem {
    float big[32 * 204];   // At (stride 200) for stage3 / rows (stride 204) for dot phases
    float aux[DD];         // xms (feat2) / a0s (hyper)
    float ms[32], rs[32];
    float csum[256];
    float wb[32], ab[32], vals[32], gs[8];
    float red[6], gred[24], lgs[8];
};

// ---- one-time transpose of the three static weights ----
__device__ __forceinline__ void transpose3(const KParams& P) {
    int g = blockIdx.x * 256 + threadIdx.x;
    const int N = 36864;
    for (; g < 3 * N; g += 384 * 256) {
        int m = g / N, e = g - m * N;
        int i = e / DD, j = e - i * DD;
        const float* src = (m == 0) ? P.W_in : (m == 1) ? P.pm_W : P.out_W;
        float* dst = (m == 0) ? P.WinT : (m == 1) ? P.pmT : P.outT;
        dst[(size_t)j * DD + i] = src[e];
    }
}

// ---- stage3: C[s,i] = sum_j A'[s,j]*W[i,j] + bias[i], W given transposed ----
// tile 32 rows x 64 cols; block 256 = 8tr x 32tc; thread = 4r x 2c.
// blockIdx -> cg = b%3 (col group), r0 = (b/3)*32.
template <int EMIT, int LNL>
__device__ __forceinline__ void stage3_phase(
    const float* A, const float* WTg, const float* bias,
    const float* stats_in, const float* lng, const float* lnb,
    float* out, float* emit_buf, Smem& S) {
    const int t = threadIdx.x;
    const int tr = t >> 5, tc = t & 31;
    const int b = blockIdx.x;
    const int cg = b % 3, c0 = cg * 64;
    const int r0 = (b / 3) * 32;
    float* At = S.big;   // stride 200

    if (LNL > 0) {
        if (t < 32) {
            int r = r0 + t;
            float s = stats_in[2 * r] + stats_in[8192 + 2 * r] + stats_in[16384 + 2 * r];
            float q = stats_in[2 * r + 1] + stats_in[8192 + 2 * r + 1]
                    + stats_in[16384 + 2 * r + 1];
            float mean = s * (1.f / 192.f);
            float var = q * (1.f / 192.f) - mean * mean;
            S.ms[t] = mean;
            S.rs[t] = rsqrtf(var + 1e-5f);
        }
        __syncthreads();
    }
    {
        const float4* A4 = (const float4*)(A + (size_t)r0 * DD);
#pragma unroll
        for (int q = 0; q < 6; q++) {
            int f = t + 256 * q;               // < 1536
            int r = f / 48, jj = f - r * 48;
            float4 v = A4[f];
            if (LNL > 0) {
                float mean = S.ms[r], rstd = S.rs[r];
                float4 g4 = ((const float4*)lng)[jj];
                float4 b4 = ((const float4*)lnb)[jj];
                v.x = (v.x - mean) * rstd * g4.x + b4.x;
                v.y = (v.y - mean) * rstd * g4.y + b4.y;
                v.z = (v.z - mean) * rstd * g4.z + b4.z;
                v.w = (v.w - mean) * rstd * g4.w + b4.w;
                if (LNL == 2) {
                    v.x = fmaxf(v.x, 0.f); v.y = fmaxf(v.y, 0.f);
                    v.z = fmaxf(v.z, 0.f); v.w = fmaxf(v.w, 0.f);
                }
            }
            *(float4*)&At[r * 200 + 4 * jj] = v;
        }
    }
    const int i0 = c0 + 2 * tc;
    const float* wp = WTg + i0;
    float bv0 = bias[i0], bv1 = bias[i0 + 1];
    float acc[4][2];
#pragma unroll
    for (int i = 0; i < 4; i++) { acc[i][0] = bv0; acc[i][1] = bv1; }
    float2 wreg[8];
#pragma unroll
    for (int jj = 0; jj < 8; jj++) wreg[jj] = *(const float2*)(wp + jj * DD);
    __syncthreads();

    const int rbase = 4 * tr;
#pragma unroll 2
    for (int jc = 0; jc < DD - 8; jc += 8) {
        float2 wcur[8];
#pragma unroll
        for (int jj = 0; jj < 8; jj++) wcur[jj] = wreg[jj];
#pragma unroll
        for (int jj = 0; jj < 8; jj++)
            wreg[jj] = *(const float2*)(wp + (jc + 8 + jj) * DD);
        float a_[4][8];
#pragma unroll
        for (int rr = 0; rr < 4; rr++) {
            float4 u = *(const float4*)&At[(rbase + rr) * 200 + jc];
            float4 v = *(const float4*)&At[(rbase + rr) * 200 + jc + 4];
            a_[rr][0] = u.x; a_[rr][1] = u.y; a_[rr][2] = u.z; a_[rr][3] = u.w;
            a_[rr][4] = v.x; a_[rr][5] = v.y; a_[rr][6] = v.z; a_[rr][7] = v.w;
        }
#pragma unroll
        for (int jj = 0; jj < 8; jj++) {
            acc[0][0] = fmaf(a_[0][jj], wcur[jj].x, acc[0][0]);
            acc[0][1] = fmaf(a_[0][jj], wcur[jj].y, acc[0][1]);
            acc[1][0] = fmaf(a_[1][jj], wcur[jj].x, acc[1][0]);
            acc[1][1] = fmaf(a_[1][jj], wcur[jj].y, acc[1][1]);
            acc[2][0] = fmaf(a_[2][jj], wcur[jj].x, acc[2][0]);
            acc[2][1] = fmaf(a_[2][jj], wcur[jj].y, acc[2][1]);
            acc[3][0] = fmaf(a_[3][jj], wcur[jj].x, acc[3][0]);
            acc[3][1] = fmaf(a_[3][jj], wcur[jj].y, acc[3][1]);
        }
    }
    {   // tail chunk jc = 184 (uses wreg directly)
        const int jc = DD - 8;
        float a_[4][8];
#pragma unroll
        for (int rr = 0; rr < 4; rr++) {
            float4 u = *(const float4*)&At[(rbase + rr) * 200 + jc];
            float4 v = *(const float4*)&At[(rbase + rr) * 200 + jc + 4];
            a_[rr][0] = u.x; a_[rr][1] = u.y; a_[rr][2] = u.z; a_[rr][3] = u.w;
            a_[rr][4] = v.x; a_[rr][5] = v.y; a_[rr][6] = v.z; a_[rr][7] = v.w;
        }
#pragma unroll
        for (int jj = 0; jj < 8; jj++) {
            acc[0][0] = fmaf(a_[0][jj], wreg[jj].x, acc[0][0]);
            acc[0][1] = fmaf(a_[0][jj], wreg[jj].y, acc[0][1]);
            acc[1][0] = fmaf(a_[1][jj], wreg[jj].x, acc[1][0]);
            acc[1][1] = fmaf(a_[1][jj], wreg[jj].y, acc[1][1]);
            acc[2][0] = fmaf(a_[2][jj], wreg[jj].x, acc[2][0]);
            acc[2][1] = fmaf(a_[2][jj], wreg[jj].y, acc[2][1]);
            acc[3][0] = fmaf(a_[3][jj], wreg[jj].x, acc[3][0]);
            acc[3][1] = fmaf(a_[3][jj], wreg[jj].y, acc[3][1]);
        }
    }

#pragma unroll
    for (int i = 0; i < 4; i++) {
        int row = r0 + rbase + i;
        *(float2*)&out[(size_t)row * DD + i0] = make_float2(acc[i][0], acc[i][1]);
    }

    if (EMIT == 2) {
#pragma unroll
        for (int i = 0; i < 4; i++) {
            float s = acc[i][0] + acc[i][1];
            float q = acc[i][0] * acc[i][0] + acc[i][1] * acc[i][1];
#pragma unroll
            for (int m = 16; m >= 1; m >>= 1) {
                s += __shfl_xor(s, m);
                q += __shfl_xor(q, m);
            }
            if (tc == 0) {
                int r = r0 + rbase + i;
                emit_buf[cg * 8192 + 2 * r] = s;
                emit_buf[cg * 8192 + 2 * r + 1] = q;
            }
        }
    } else if (EMIT == 1) {
        float cs0 = acc[0][0] + acc[1][0] + acc[2][0] + acc[3][0];
        float cs1 = acc[0][1] + acc[1][1] + acc[2][1] + acc[3][1];
        cs0 += __shfl_xor(cs0, 32);
        cs1 += __shfl_xor(cs1, 32);
        int w = t >> 6;
        if ((t & 63) < 32) {
            S.csum[w * 64 + 2 * tc] = cs0;
            S.csum[w * 64 + 2 * tc + 1] = cs1;
        }
        __syncthreads();
        if (t < 64) {
            float s = S.csum[t] + S.csum[64 + t] + S.csum[128 + t] + S.csum[192 + t];
            atomicAdd(&emit_buf[c0 + t], s);
        }
    }
}

// ---- feat2: a_pre[i] += sum_{j in chunk} xm[j]*(feat_W[k]+feat_AW[k,:]@xm+feat_Ab[k])
__device__ __forceinline__ void feat2_phase(const KParams& P, Smem& S) {
    const int t = threadIdx.x;
    float* rows = S.big;   // stride 204
    if (t < DD) S.aux[t] = P.xm_sum[t] * (1.f / 4096.f);
    const int r = t >> 3, p = t & 7;
    for (int q3 = 0; q3 < 3; q3++) {
        const int c = blockIdx.x + 384 * q3;   // < 1152
        const int k0 = c * 32;
        __syncthreads();
        if (t < 32) { S.wb[t] = P.feat_W[k0 + t]; S.ab[t] = P.feat_Ab[k0 + t]; }
        const float4* src4 = (const float4*)(P.feat_AW + (size_t)k0 * DD);
#pragma unroll
        for (int q = 0; q < 6; q++) {
            int f = t + 256 * q;
            int rr = f / 48, jj = f - rr * 48;
            *(float4*)&rows[rr * 204 + 4 * jj] = src4[f];
        }
        __syncthreads();
        float acc = 0.f;
#pragma unroll
        for (int q = 0; q < 6; q++) {
            int jo = p * 24 + 4 * q;
            float4 w = *(const float4*)&rows[r * 204 + jo];
            float4 aa = *(const float4*)&S.aux[jo];
            acc = fmaf(w.x, aa.x, acc); acc = fmaf(w.y, aa.y, acc);
            acc = fmaf(w.z, aa.z, acc); acc = fmaf(w.w, aa.w, acc);
        }
        acc += __shfl_xor(acc, 1);
        acc += __shfl_xor(acc, 2);
        acc += __shfl_xor(acc, 4);
        if (p == 0) S.vals[r] = acc + S.wb[r] + S.ab[r];
        __syncthreads();
        const int j0 = k0 % DD;
        if (t < 32) {
            float cp = S.vals[t] * S.aux[j0 + t];
#pragma unroll
            for (int m = 16; m >= 1; m >>= 1) cp += __shfl_xor(cp, m);
            if (t == 0) atomicAdd(&P.a_pre[k0 / DD], cp);
        }
    }
}

// ---- vec: a0 = LN(a_pre+feat_b); gate = softmax(a0@gate_W^T+gate_b); b_moe ----
__device__ __forceinline__ void vec_phase(const KParams& P, Smem& S) {
    const int t = threadIdx.x;
    const int w = t >> 6;
    float v = (t < DD) ? (P.a_pre[t] + P.feat_b[t]) : 0.f;
    float s = v, q = v * v;
#pragma unroll
    for (int m = 32; m >= 1; m >>= 1) { s += __shfl_xor(s, m); q += __shfl_xor(q, m); }
    if (((t & 63) == 0) && w < 3) { S.red[w] = s; S.red[3 + w] = q; }
    __syncthreads();
    float a0v = 0.f;
    if (t < DD) {
        float Ssum = S.red[0] + S.red[1] + S.red[2];
        float Q = S.red[3] + S.red[4] + S.red[5];
        float mean = Ssum * (1.f / 192.f);
        float var = Q * (1.f / 192.f) - mean * mean;
        float rstd = rsqrtf(var + 1e-5f);
        a0v = (v - mean) * rstd * P.an_g[t] + P.an_b[t];
        P.a0[t] = a0v;
    }
#pragma unroll
    for (int e = 0; e < 8; e++) {
        float xv = (t < DD) ? a0v * P.gate_W[e * DD + t] : 0.f;
#pragma unroll
        for (int m = 32; m >= 1; m >>= 1) xv += __shfl_xor(xv, m);
        if (((t & 63) == 0) && w < 3) S.gred[w * 8 + e] = xv;
    }
    __syncthreads();
    if (t < 8) S.lgs[t] = S.gred[t] + S.gred[8 + t] + S.gred[16 + t] + P.gate_b[t];
    __syncthreads();
    if (t == 0) {
        float mx = S.lgs[0];
        for (int e = 1; e < 8; e++) mx = fmaxf(mx, S.lgs[e]);
        float sum = 0.f, ex[8];
        for (int e = 0; e < 8; e++) { ex[e] = expf(S.lgs[e] - mx); sum += ex[e]; }
        for (int e = 0; e < 8; e++) S.lgs[e] = ex[e] / sum;
    }
    __syncthreads();
    if (t < 8) P.gate[t] = S.lgs[t];
    if (t < DD) {
        float bm = 0.f;
#pragma unroll
        for (int e = 0; e < 8; e++) bm = fmaf(S.lgs[e], P.ex_b[e * DD + t], bm);
        P.b_moe[t] = bm;
    }
}

// ---- hyper: 9 chunks/block (3 Wt + 3 Wc + 3 MoE); writes TRANSPOSED ----
__device__ __forceinline__ void hyper_phase(const KParams& P, Smem& S) {
    const int t = threadIdx.x;
    float* rows = S.big;   // stride 204
    if (t < DD) S.aux[t] = P.a0[t];
    if (t < 8) S.gs[t] = P.gate[t];
    const int r = t >> 3, p = t & 7;
    for (int q9 = 0; q9 < 9; q9++) {
        const int c = blockIdx.x + 384 * q9;   // < 3456
        if (c < 2304) {
            const float* AW; const float* WB; const float* AB; float* dstT;
            int k0;
            if (c < 1152) { AW = P.tm_AW; WB = P.tm_W; AB = P.tm_Ab; dstT = P.WtT; k0 = c * 32; }
            else { AW = P.cm_AW; WB = P.cm_W; AB = P.cm_Ab; dstT = P.WcT; k0 = (c - 1152) * 32; }
            __syncthreads();
            if (t < 32) { S.wb[t] = WB[k0 + t]; S.ab[t] = AB[k0 + t]; }
            const float4* src4 = (const float4*)(AW + (size_t)k0 * DD);
#pragma unroll
            for (int q = 0; q < 6; q++) {
                int f = t + 256 * q;
                int rr = f / 48, jj = f - rr * 48;
                *(float4*)&rows[rr * 204 + 4 * jj] = src4[f];
            }
            __syncthreads();
            float acc = 0.f;
#pragma unroll
            for (int q = 0; q < 6; q++) {
                int jo = p * 24 + 4 * q;
                float4 w = *(const float4*)&rows[r * 204 + jo];
                float4 aa = *(const float4*)&S.aux[jo];
                acc = fmaf(w.x, aa.x, acc); acc = fmaf(w.y, aa.y, acc);
                acc = fmaf(w.z, aa.z, acc); acc = fmaf(w.w, aa.w, acc);
            }
            acc += __shfl_xor(acc, 1);
            acc += __shfl_xor(acc, 2);
            acc += __shfl_xor(acc, 4);
            if (p == 0) S.vals[r] = acc + S.wb[r] + S.ab[r];
            __syncthreads();
            if (t < 32) {
                int i = k0 / DD, j = k0 - i * DD + t;
                dstT[(size_t)j * DD + i] = S.vals[t];
            }
        } else {
            const int k0 = (c - 2304) * 32;
            float macc = 0.f;
            for (int e = 0; e < 8; e++) {
                __syncthreads();
                const float4* src4 =
                    (const float4*)(P.ex_AW + (size_t)e * 36864 * DD + (size_t)k0 * DD);
#pragma unroll
                for (int q = 0; q < 6; q++) {
                    int f = t + 256 * q;
                    int rr = f / 48, jj = f - rr * 48;
                    *(float4*)&rows[rr * 204 + 4 * jj] = src4[f];
                }
                __syncthreads();
                float acc = 0.f;
#pragma unroll
                for (int q = 0; q < 6; q++) {
                    int jo = p * 24 + 4 * q;
                    float4 w = *(const float4*)&rows[r * 204 + jo];
                    float4 aa = *(const float4*)&S.aux[jo];
                    acc = fmaf(w.x, aa.x, acc); acc = fmaf(w.y, aa.y, acc);
                    acc = fmaf(w.z, aa.z, acc); acc = fmaf(w.w, aa.w, acc);
                }
                acc += __shfl_xor(acc, 1);
                acc += __shfl_xor(acc, 2);
                acc += __shfl_xor(acc, 4);
                if (p == 0) S.vals[r] = acc;
                __syncthreads();
                if (t < 32) {
                    float we = P.ex_W[(size_t)e * 36864 + k0 + t];
                    float ae = P.ex_Ab[(size_t)e * 36864 + k0 + t];
                    macc = fmaf(S.gs[e], S.vals[t] + we + ae, macc);
                }
            }
            if (t < 32) {
                int i = k0 / DD, j = k0 - i * DD + t;
                P.WmoeT[(size_t)j * DD + i] = macc;
            }
        }
    }
}

// =======================================================================
// Fused cooperative kernel: whole model in one launch, grid 384 x 256.
// =======================================================================
__global__ __launch_bounds__(256, 2) void fused_k(KParams P) {
    cg::grid_group grid = cg::this_grid();
    __shared__ Smem S;
    transpose3(P);
    grid.sync();
    stage3_phase<1, 0>(P.x, P.WinT, P.b_in, nullptr, nullptr, nullptr, P.B0, P.xm_sum, S);
    grid.sync();
    feat2_phase(P, S);
    grid.sync();
    if (blockIdx.x == 0) vec_phase(P, S);
    grid.sync();
    hyper_phase(P, S);
    grid.sync();
    stage3_phase<2, 0>(P.B0, P.WtT, P.tm_b, nullptr, nullptr, nullptr, P.B1, P.st1, S);
    grid.sync();
    stage3_phase<2, 1>(P.B1, P.WcT, P.cm_b, P.st1, P.tn_g, P.tn_b, P.B0, P.st2, S);
    grid.sync();
    stage3_phase<0, 1>(P.B0, P.pmT, P.pm_b, P.st2, P.cn_g, P.cn_b, P.B1, nullptr, S);
    grid.sync();
    stage3_phase<2, 0>(P.B1, P.WmoeT, P.b_moe, nullptr, nullptr, nullptr, P.B0, P.st3, S);
    grid.sync();
    stage3_phase<0, 2>(P.B0, P.outT, P.out_b, P.st3, P.mn_g, P.mn_b, P.out, nullptr, S);
}

// ---- non-cooperative fallback wrappers (same device code, 10 launches) ----
__global__ __launch_bounds__(256, 2) void ph_tr_k(KParams P) { transpose3(P); }
__global__ __launch_bounds__(256, 2) void ph_s1_k(KParams P) {
    __shared__ Smem S;
    stage3_phase<1, 0>(P.x, P.WinT, P.b_in, nullptr, nullptr, nullptr, P.B0, P.xm_sum, S);
}
__global__ __launch_bounds__(256, 2) void ph_f2_k(KParams P) { __shared__ Smem S; feat2_phase(P, S); }
__global__ __launch_bounds__(256, 2) void ph_vec_k(KParams P) { __shared__ Smem S; vec_phase(P, S); }
__global__ __launch_bounds__(256, 2) void ph_hy_k(KParams P) { __shared__ Smem S; hyper_phase(P, S); }
__global__ __launch_bounds__(256, 2) void ph_s2_k(KParams P) {
    __shared__ Smem S;
    stage3_phase<2, 0>(P.B0, P.WtT, P.tm_b, nullptr, nullptr, nullptr, P.B1, P.st1, S);
}
__global__ __launch_bounds__(256, 2) void ph_s3_k(KParams P) {
    __shared__ Smem S;
    stage3_phase<2, 1>(P.B1, P.WcT, P.cm_b, P.st1, P.tn_g, P.tn_b, P.B0, P.st2, S);
}
__global__ __launch_bounds__(256, 2) void ph_s4_k(KParams P) {
    __shared__ Smem S;
    stage3_phase<0, 1>(P.B0, P.pmT, P.pm_b, P.st2, P.cn_g, P.cn_b, P.B1, nullptr, S);
}
__global__ __launch_bounds__(256, 2) void ph_s5_k(KParams P) {
    __shared__ Smem S;
    stage3_phase<2, 0>(P.B1, P.WmoeT, P.b_moe, nullptr, nullptr, nullptr, P.B0, P.st3, S);
}
__global__ __launch_bounds__(256, 2) void ph_s6_k(KParams P) {
    __shared__ Smem S;
    stage3_phase<0, 2>(P.B0, P.outT, P.out_b, P.st3, P.mn_g, P.mn_b, P.out, nullptr, S);
}

// =======================================================================
extern "C" void kernel_launch(void* const* d_in, const int* in_sizes, int n_in,
                              void* d_out, int out_size, void* d_ws, size_t ws_size,
                              hipStream_t stream) {
    (void)in_sizes; (void)n_in; (void)out_size; (void)ws_size;
    float* ws = (float*)d_ws;

    KParams P;
    P.x       = (const float*)d_in[0];
    P.W_in    = (const float*)d_in[1];
    P.b_in    = (const float*)d_in[2];
    P.feat_W  = (const float*)d_in[3];
    P.feat_b  = (const float*)d_in[4];
    P.feat_AW = (const float*)d_in[5];
    P.feat_Ab = (const float*)d_in[6];
    P.an_g    = (const float*)d_in[7];
    P.an_b    = (const float*)d_in[8];
    P.tm_W    = (const float*)d_in[9];
    P.tm_b    = (const float*)d_in[10];
    P.tm_AW   = (const float*)d_in[11];
    P.tm_Ab   = (const float*)d_in[12];
    P.tn_g    = (const float*)d_in[13];
    P.tn_b    = (const float*)d_in[14];
    P.cm_W    = (const float*)d_in[15];
    P.cm_b    = (const float*)d_in[16];
    P.cm_AW   = (const float*)d_in[17];
    P.cm_Ab   = (const float*)d_in[18];
    P.cn_g    = (const float*)d_in[19];
    P.cn_b    = (const float*)d_in[20];
    P.pm_W    = (const float*)d_in[21];
    P.pm_b    = (const float*)d_in[22];
    P.gate_W  = (const float*)d_in[23];
    P.gate_b  = (const float*)d_in[24];
    P.ex_W    = (const float*)d_in[25];
    P.ex_b    = (const float*)d_in[26];
    P.ex_AW   = (const float*)d_in[27];
    P.ex_Ab   = (const float*)d_in[28];
    P.mn_g    = (const float*)d_in[29];
    P.mn_b    = (const float*)d_in[30];
    P.out_W   = (const float*)d_in[31];
    P.out_b   = (const float*)d_in[32];

    P.B0     = ws;                 // 786432
    P.B1     = ws + 786432;        // 786432
    P.xm_sum = ws + 1572864;       // 192  [zeroed]
    P.a_pre  = ws + 1573056;       // 192  [zeroed]
    P.WmoeT  = ws + 1573248;       // 36864
    P.WtT    = ws + 1610112;       // 36864
    P.WcT    = ws + 1646976;       // 36864
    P.st1    = ws + 1683840;       // 3*8192
    P.st2    = ws + 1708416;       // 3*8192
    P.st3    = ws + 1732992;       // 3*8192
    P.a0     = ws + 1757568;       // 192
    P.gate   = ws + 1757760;       // 8
    P.b_moe  = ws + 1757768;       // 192
    P.WinT   = ws + 1758208;       // 36864
    P.pmT    = ws + 1795072;       // 36864
    P.outT   = ws + 1831936;       // 36864
    P.out    = (float*)d_out;

    hipMemsetAsync(P.xm_sum, 0, (size_t)384 * sizeof(float), stream);

    void* args[] = { (void*)&P };
    hipError_t err = hipLaunchCooperativeKernel((void*)fused_k, dim3(384), dim3(256),
                                                args, 0, stream);
    if (err != hipSuccess) {
        // fallback: same phases as separate launches
        ph_tr_k<<<384, 256, 0, stream>>>(P);
        ph_s1_k<<<384, 256, 0, stream>>>(P);
        ph_f2_k<<<384, 256, 0, stream>>>(P);
        ph_vec_k<<<1, 256, 0, stream>>>(P);
        ph_hy_k<<<384, 256, 0, stream>>>(P);
        ph_s2_k<<<384, 256, 0, stream>>>(P);
        ph_s3_k<<<384, 256, 0, stream>>>(P);
        ph_s4_k<<<384, 256, 0, stream>>>(P);
        ph_s5_k<<<384, 256, 0, stream>>>(P);
        ph_s6_k<<<384, 256, 0, stream>>>(P);
    }
}

// Round 3
// 559.301 us; speedup vs baseline: 1.8328x; 1.8328x over previous
//
#include <hip/hip_runtime.h>

#define DD 192

// =======================================================================
// tr3_k: one-time transpose of the three static weights (W_in, pm_W, out_W)
// grid 432 x 256 = 110592 = 3 * 36864 elements.
// =======================================================================
__global__ __launch_bounds__(256) void tr3_k(
    const float* __restrict__ W_in, const float* __restrict__ pm_W,
    const float* __restrict__ out_W, float* __restrict__ WinT,
    float* __restrict__ pmT, float* __restrict__ outT) {
    int g = blockIdx.x * 256 + threadIdx.x;   // < 110592
    int m = g / 36864, e = g - m * 36864;
    int i = e / DD, j = e - i * DD;
    const float* s = (m == 0) ? W_in : (m == 1) ? pm_W : out_W;
    float* d = (m == 0) ? WinT : (m == 1) ? pmT : outT;
    d[(size_t)j * DD + i] = s[e];
}

// =======================================================================
// stage3_k v3: C[s,i] = sum_j A'[s,j] * WT[j,i] + bias[i]   (W TRANSPOSED)
//   A' = A (LNL=0), LN(A) (LNL=1), relu(LN(A)) (LNL=2)
//   EMIT: 0 none, 1 colsum (atomic emit[i] += sum_s C[s,i]),
//         2 stats (emit[cg*8192+2r] = rowsum, +1 = rowsumsq; non-atomic)
// Tile 16 rows x 64 cols; 256 thr = 8tr x 32tc; thread = 2r x 2c.
// Grid 768 = 3 colgroups x 256 rowgroups. LDS = A tile only (12.8 KB) so
// ~6+ blocks/CU are resident; W streamed from global (L1/L2-hot, 48 KB
// slice shared by 256 blocks) with an 8-deep float2 prefetch pipeline.
// =======================================================================
template <int EMIT, int LNL>
__global__ __launch_bounds__(256) void stage3_k(
    const float* __restrict__ A, const float* __restrict__ WTg,
    const float* __restrict__ bias,
    const float* __restrict__ stats_in, const float* __restrict__ lng,
    const float* __restrict__ lnb,
    float* __restrict__ out, float* __restrict__ emit_buf) {
    __shared__ float At[16 * 200];   // stride 200 words
    __shared__ float ms[16], rs[16];
    __shared__ float csum[256];

    const int t = threadIdx.x;
    const int tr = t >> 5, tc = t & 31;
    const int b = blockIdx.x;
    const int cg = b % 3, c0 = cg * 64;
    const int r0 = (b / 3) * 16;

    if (LNL > 0) {
        if (t < 16) {
            int r = r0 + t;
            float s = stats_in[2 * r] + stats_in[8192 + 2 * r] + stats_in[16384 + 2 * r];
            float q = stats_in[2 * r + 1] + stats_in[8192 + 2 * r + 1]
                    + stats_in[16384 + 2 * r + 1];
            float mean = s * (1.f / 192.f);
            float var = q * (1.f / 192.f) - mean * mean;
            ms[t] = mean;
            rs[t] = rsqrtf(var + 1e-5f);
        }
        __syncthreads();
    }

    // ---- stage A tile (16 x 192) with LN(+ReLU) on load ----
    {
        const float4* A4 = (const float4*)(A + (size_t)r0 * DD);
#pragma unroll
        for (int q = 0; q < 3; q++) {
            int f = t + 256 * q;               // < 768
            int r = f / 48, jj = f - r * 48;
            float4 v = A4[f];
            if (LNL > 0) {
                float mean = ms[r], rstd = rs[r];
                float4 g4 = ((const float4*)lng)[jj];
                float4 b4 = ((const float4*)lnb)[jj];
                v.x = (v.x - mean) * rstd * g4.x + b4.x;
                v.y = (v.y - mean) * rstd * g4.y + b4.y;
                v.z = (v.z - mean) * rstd * g4.z + b4.z;
                v.w = (v.w - mean) * rstd * g4.w + b4.w;
                if (LNL == 2) {
                    v.x = fmaxf(v.x, 0.f); v.y = fmaxf(v.y, 0.f);
                    v.z = fmaxf(v.z, 0.f); v.w = fmaxf(v.w, 0.f);
                }
            }
            *(float4*)&At[r * 200 + 4 * jj] = v;
        }
    }

    const int i0 = c0 + 2 * tc;
    const float* wp = WTg + i0;
    float bv0 = bias[i0], bv1 = bias[i0 + 1];
    float acc[2][2];
#pragma unroll
    for (int i = 0; i < 2; i++) { acc[i][0] = bv0; acc[i][1] = bv1; }
    float2 wreg[8];
#pragma unroll
    for (int jj = 0; jj < 8; jj++) wreg[jj] = *(const float2*)(wp + jj * DD);
    __syncthreads();

    const int rbase = 2 * tr;
#pragma unroll 2
    for (int jc = 0; jc < DD - 8; jc += 8) {
        float2 wcur[8];
#pragma unroll
        for (int jj = 0; jj < 8; jj++) wcur[jj] = wreg[jj];
#pragma unroll
        for (int jj = 0; jj < 8; jj++)
            wreg[jj] = *(const float2*)(wp + (jc + 8 + jj) * DD);
        float a_[2][8];
#pragma unroll
        for (int rr = 0; rr < 2; rr++) {
            float4 u = *(const float4*)&At[(rbase + rr) * 200 + jc];
            float4 v = *(const float4*)&At[(rbase + rr) * 200 + jc + 4];
            a_[rr][0] = u.x; a_[rr][1] = u.y; a_[rr][2] = u.z; a_[rr][3] = u.w;
            a_[rr][4] = v.x; a_[rr][5] = v.y; a_[rr][6] = v.z; a_[rr][7] = v.w;
        }
#pragma unroll
        for (int jj = 0; jj < 8; jj++) {
            acc[0][0] = fmaf(a_[0][jj], wcur[jj].x, acc[0][0]);
            acc[0][1] = fmaf(a_[0][jj], wcur[jj].y, acc[0][1]);
            acc[1][0] = fmaf(a_[1][jj], wcur[jj].x, acc[1][0]);
            acc[1][1] = fmaf(a_[1][jj], wcur[jj].y, acc[1][1]);
        }
    }
    {   // tail chunk jc = 184
        const int jc = DD - 8;
        float a_[2][8];
#pragma unroll
        for (int rr = 0; rr < 2; rr++) {
            float4 u = *(const float4*)&At[(rbase + rr) * 200 + jc];
            float4 v = *(const float4*)&At[(rbase + rr) * 200 + jc + 4];
            a_[rr][0] = u.x; a_[rr][1] = u.y; a_[rr][2] = u.z; a_[rr][3] = u.w;
            a_[rr][4] = v.x; a_[rr][5] = v.y; a_[rr][6] = v.z; a_[rr][7] = v.w;
        }
#pragma unroll
        for (int jj = 0; jj < 8; jj++) {
            acc[0][0] = fmaf(a_[0][jj], wreg[jj].x, acc[0][0]);
            acc[0][1] = fmaf(a_[0][jj], wreg[jj].y, acc[0][1]);
            acc[1][0] = fmaf(a_[1][jj], wreg[jj].x, acc[1][0]);
            acc[1][1] = fmaf(a_[1][jj], wreg[jj].y, acc[1][1]);
        }
    }

#pragma unroll
    for (int i = 0; i < 2; i++) {
        int row = r0 + rbase + i;
        *(float2*)&out[(size_t)row * DD + i0] = make_float2(acc[i][0], acc[i][1]);
    }

    if (EMIT == 2) {
#pragma unroll
        for (int i = 0; i < 2; i++) {
            float s = acc[i][0] + acc[i][1];
            float q = acc[i][0] * acc[i][0] + acc[i][1] * acc[i][1];
#pragma unroll
            for (int m = 16; m >= 1; m >>= 1) {
                s += __shfl_xor(s, m);
                q += __shfl_xor(q, m);
            }
            if (tc == 0) {
                int r = r0 + rbase + i;
                emit_buf[cg * 8192 + 2 * r] = s;
                emit_buf[cg * 8192 + 2 * r + 1] = q;
            }
        }
    } else if (EMIT == 1) {
        float cs0 = acc[0][0] + acc[1][0];
        float cs1 = acc[0][1] + acc[1][1];
        cs0 += __shfl_xor(cs0, 32);   // fold the wave's two tr rows
        cs1 += __shfl_xor(cs1, 32);
        int w = t >> 6;
        if ((t & 63) < 32) {
            csum[w * 64 + 2 * tc] = cs0;
            csum[w * 64 + 2 * tc + 1] = cs1;
        }
        __syncthreads();
        if (t < 64) {
            float s = csum[t] + csum[64 + t] + csum[128 + t] + csum[192 + t];
            atomicAdd(&emit_buf[c0 + t], s);
        }
    }
}

// =======================================================================
// hyper_k: hypernet weights, 32 AW-rows per block, uniform grid 11520
// (load-balanced, oversubscribed for HBM latency hiding). Writes the
// outputs TRANSPOSED (WtT/WcT row j, col i). MoE: gate-weighted atomicAdd
// into zeroed WmoeT.
// =======================================================================
__global__ __launch_bounds__(256) void hyper_k(
    const float* __restrict__ tm_W, const float* __restrict__ tm_AW,
    const float* __restrict__ tm_Ab, const float* __restrict__ cm_W,
    const float* __restrict__ cm_AW, const float* __restrict__ cm_Ab,
    const float* __restrict__ ex_W, const float* __restrict__ ex_AW,
    const float* __restrict__ ex_Ab, const float* __restrict__ a0g,
    const float* __restrict__ gateg, float* __restrict__ WtT,
    float* __restrict__ WcT, float* __restrict__ WmoeT) {
    __shared__ float a0s[DD];
    __shared__ float rows[32 * 204];
    __shared__ float wb[32], ab[32], vals[32];
    const int t = threadIdx.x;
    const int b = blockIdx.x;
    const float* AW; const float* WB; const float* AB;
    int k0, mode, e = 0;
    if (b < 1152)      { mode = 0; AW = tm_AW; WB = tm_W; AB = tm_Ab; k0 = b * 32; }
    else if (b < 2304) { mode = 1; AW = cm_AW; WB = cm_W; AB = cm_Ab; k0 = (b - 1152) * 32; }
    else {
        mode = 2; int bb = b - 2304; e = bb / 1152; k0 = (bb - e * 1152) * 32;
        AW = ex_AW + (size_t)e * 36864 * DD;
        WB = ex_W + (size_t)e * 36864;
        AB = ex_Ab + (size_t)e * 36864;
    }
    if (t < DD) a0s[t] = a0g[t];
    if (t < 32) { wb[t] = WB[k0 + t]; ab[t] = AB[k0 + t]; }
    const float4* src4 = (const float4*)(AW + (size_t)k0 * DD);
#pragma unroll
    for (int q = 0; q < 6; q++) {
        int fidx = t + 256 * q;            // < 1536
        int r = fidx / 48, jj = fidx - r * 48;
        *(float4*)&rows[r * 204 + 4 * jj] = src4[fidx];
    }
    __syncthreads();
    const int r = t >> 3, p = t & 7;
    float acc = 0.f;
#pragma unroll
    for (int q = 0; q < 6; q++) {
        int jo = p * 24 + 4 * q;
        float4 w = *(const float4*)&rows[r * 204 + jo];
        float4 aa = *(const float4*)&a0s[jo];
        acc = fmaf(w.x, aa.x, acc); acc = fmaf(w.y, aa.y, acc);
        acc = fmaf(w.z, aa.z, acc); acc = fmaf(w.w, aa.w, acc);
    }
    acc += __shfl_xor(acc, 1);
    acc += __shfl_xor(acc, 2);
    acc += __shfl_xor(acc, 4);
    if (p == 0) vals[r] = acc + wb[r] + ab[r];
    __syncthreads();
    if (t < 32) {
        // element (i, jb + t) of the 192x192 weight; 32-chunk stays in one i
        int i = k0 / DD, jb = k0 - i * DD;
        if (mode == 0) WtT[(size_t)(jb + t) * DD + i] = vals[t];
        else if (mode == 1) WcT[(size_t)(jb + t) * DD + i] = vals[t];
        else atomicAdd(&WmoeT[(size_t)(jb + t) * DD + i], gateg[e] * vals[t]);
    }
}

// =======================================================================
// feat2_k: a_pre[i] += sum_{j in chunk} xm[j]*(feat_W[k]+feat_AW[k,:]@xm+feat_Ab[k])
// =======================================================================
__global__ __launch_bounds__(256) void feat2_k(
    const float* __restrict__ feat_W, const float* __restrict__ feat_AW,
    const float* __restrict__ feat_Ab, const float* __restrict__ xm_sum,
    float* __restrict__ a_pre) {
    __shared__ float xms[DD];
    __shared__ float rows[32 * 204];
    __shared__ float wb[32], ab[32], vals[32];
    const int t = threadIdx.x;
    const int k0 = blockIdx.x * 32;
    if (t < DD) xms[t] = xm_sum[t] * (1.f / 4096.f);
    if (t < 32) { wb[t] = feat_W[k0 + t]; ab[t] = feat_Ab[k0 + t]; }
    const float4* src4 = (const float4*)(feat_AW + (size_t)k0 * DD);
#pragma unroll
    for (int q = 0; q < 6; q++) {
        int fidx = t + 256 * q;
        int r = fidx / 48, jj = fidx - r * 48;
        *(float4*)&rows[r * 204 + 4 * jj] = src4[fidx];
    }
    __syncthreads();
    const int r = t >> 3, p = t & 7;
    float acc = 0.f;
#pragma unroll
    for (int q = 0; q < 6; q++) {
        int jo = p * 24 + 4 * q;
        float4 w = *(const float4*)&rows[r * 204 + jo];
        float4 aa = *(const float4*)&xms[jo];
        acc = fmaf(w.x, aa.x, acc); acc = fmaf(w.y, aa.y, acc);
        acc = fmaf(w.z, aa.z, acc); acc = fmaf(w.w, aa.w, acc);
    }
    acc += __shfl_xor(acc, 1);
    acc += __shfl_xor(acc, 2);
    acc += __shfl_xor(acc, 4);
    if (p == 0) vals[r] = acc + wb[r] + ab[r];
    __syncthreads();
    const int j0 = k0 % DD;   // chunk of 32 stays within one output i
    if (t < 32) {
        float c = vals[t] * xms[j0 + t];
#pragma unroll
        for (int m = 16; m >= 1; m >>= 1) c += __shfl_xor(c, m);
        if (t == 0) atomicAdd(&a_pre[k0 / DD], c);
    }
}

// =======================================================================
// vec_k: a0 = LN(a_pre + feat_b); gate = softmax(a0@gate_W^T + gate_b);
//        b_moe = sum_e gate[e]*ex_b[e,:]
// =======================================================================
__global__ __launch_bounds__(192) void vec_k(
    const float* __restrict__ a_pre, const float* __restrict__ feat_b,
    const float* __restrict__ an_g, const float* __restrict__ an_b,
    const float* __restrict__ gate_W, const float* __restrict__ gate_b,
    const float* __restrict__ ex_b, float* __restrict__ a0g,
    float* __restrict__ gateg, float* __restrict__ b_moe) {
    __shared__ float red[6];
    __shared__ float gred[24];
    __shared__ float lgs[8];
    const int t = threadIdx.x;
    const int w = t >> 6;
    float v = a_pre[t] + feat_b[t];
    float s = v, q = v * v;
#pragma unroll
    for (int m = 32; m >= 1; m >>= 1) { s += __shfl_xor(s, m); q += __shfl_xor(q, m); }
    if ((t & 63) == 0) { red[w] = s; red[3 + w] = q; }
    __syncthreads();
    float S = red[0] + red[1] + red[2];
    float Q = red[3] + red[4] + red[5];
    float mean = S * (1.f / 192.f);
    float var = Q * (1.f / 192.f) - mean * mean;
    float rstd = rsqrtf(var + 1e-5f);
    float a0v = (v - mean) * rstd * an_g[t] + an_b[t];
    a0g[t] = a0v;
#pragma unroll
    for (int e = 0; e < 8; e++) {
        float x = a0v * gate_W[e * DD + t];
#pragma unroll
        for (int m = 32; m >= 1; m >>= 1) x += __shfl_xor(x, m);
        if ((t & 63) == 0) gred[w * 8 + e] = x;
    }
    __syncthreads();
    if (t < 8) lgs[t] = gred[t] + gred[8 + t] + gred[16 + t] + gate_b[t];
    __syncthreads();
    if (t == 0) {
        float mx = lgs[0];
        for (int e = 1; e < 8; e++) mx = fmaxf(mx, lgs[e]);
        float sum = 0.f, ex[8];
        for (int e = 0; e < 8; e++) { ex[e] = expf(lgs[e] - mx); sum += ex[e]; }
        for (int e = 0; e < 8; e++) lgs[e] = ex[e] / sum;
    }
    __syncthreads();
    if (t < 8) gateg[t] = lgs[t];
    float bm = 0.f;
#pragma unroll
    for (int e = 0; e < 8; e++) bm = fmaf(lgs[e], ex_b[e * DD + t], bm);
    b_moe[t] = bm;
}

// =======================================================================
extern "C" void kernel_launch(void* const* d_in, const int* in_sizes, int n_in,
                              void* d_out, int out_size, void* d_ws, size_t ws_size,
                              hipStream_t stream) {
    (void)in_sizes; (void)n_in; (void)out_size; (void)ws_size;
    const float* x       = (const float*)d_in[0];
    const float* W_in    = (const float*)d_in[1];
    const float* b_in    = (const float*)d_in[2];
    const float* feat_W  = (const float*)d_in[3];
    const float* feat_b  = (const float*)d_in[4];
    const float* feat_AW = (const float*)d_in[5];
    const float* feat_Ab = (const float*)d_in[6];
    const float* an_g    = (const float*)d_in[7];
    const float* an_b    = (const float*)d_in[8];
    const float* tm_W    = (const float*)d_in[9];
    const float* tm_b    = (const float*)d_in[10];
    const float* tm_AW   = (const float*)d_in[11];
    const float* tm_Ab   = (const float*)d_in[12];
    const float* tn_g    = (const float*)d_in[13];
    const float* tn_b    = (const float*)d_in[14];
    const float* cm_W    = (const float*)d_in[15];
    const float* cm_b    = (const float*)d_in[16];
    const float* cm_AW   = (const float*)d_in[17];
    const float* cm_Ab   = (const float*)d_in[18];
    const float* cn_g    = (const float*)d_in[19];
    const float* cn_b    = (const float*)d_in[20];
    const float* pm_W    = (const float*)d_in[21];
    const float* pm_b    = (const float*)d_in[22];
    const float* gate_W  = (const float*)d_in[23];
    const float* gate_b  = (const float*)d_in[24];
    const float* ex_W    = (const float*)d_in[25];
    const float* ex_b    = (const float*)d_in[26];
    const float* ex_AW   = (const float*)d_in[27];
    const float* ex_Ab   = (const float*)d_in[28];
    const float* mn_g    = (const float*)d_in[29];
    const float* mn_b    = (const float*)d_in[30];
    const float* out_W   = (const float*)d_in[31];
    const float* out_b   = (const float*)d_in[32];

    float* ws = (float*)d_ws;
    float* B0     = ws;                 // 786432
    float* B1     = ws + 786432;        // 786432
    float* xm_sum = ws + 1572864;       // 192   [zeroed]
    float* a_pre  = ws + 1573056;       // 192   [zeroed]
    float* WmoeT  = ws + 1573248;       // 36864 [zeroed, atomic accum]
    float* WtT    = ws + 1610112;       // 36864
    float* WcT    = ws + 1646976;       // 36864
    float* st1    = ws + 1683840;       // 3*8192
    float* st2    = ws + 1708416;       // 3*8192
    float* st3    = ws + 1732992;       // 3*8192
    float* a0     = ws + 1757568;       // 192
    float* gate   = ws + 1757760;       // 8
    float* b_moe  = ws + 1757768;       // 192
    float* WinT   = ws + 1758208;       // 36864
    float* pmT    = ws + 1795072;       // 36864
    float* outT   = ws + 1831936;       // 36864

    // zero xm_sum + a_pre + WmoeT (contiguous 37248 floats)
    hipMemsetAsync(xm_sum, 0, (size_t)37248 * sizeof(float), stream);

    tr3_k<<<432, 256, 0, stream>>>(W_in, pm_W, out_W, WinT, pmT, outT);
    // S1: h = x @ W_in^T + b_in ; colsum -> xm_sum        (x -> B0)
    stage3_k<1, 0><<<768, 256, 0, stream>>>(x, WinT, b_in, nullptr, nullptr, nullptr,
                                            B0, xm_sum);
    feat2_k<<<1152, 256, 0, stream>>>(feat_W, feat_AW, feat_Ab, xm_sum, a_pre);
    vec_k<<<1, 192, 0, stream>>>(a_pre, feat_b, an_g, an_b, gate_W, gate_b, ex_b,
                                 a0, gate, b_moe);
    hyper_k<<<11520, 256, 0, stream>>>(tm_W, tm_AW, tm_Ab, cm_W, cm_AW, cm_Ab,
                                       ex_W, ex_AW, ex_Ab, a0, gate, WtT, WcT, WmoeT);
    // S2: tpre = h @ Wt^T + tm_b ; stats -> st1           (B0 -> B1)
    stage3_k<2, 0><<<768, 256, 0, stream>>>(B0, WtT, tm_b, nullptr, nullptr, nullptr,
                                            B1, st1);
    // S3: cpre = LN_tn(tpre) @ Wc^T + cm_b ; stats -> st2 (B1 -> B0)
    stage3_k<2, 1><<<768, 256, 0, stream>>>(B1, WcT, cm_b, st1, tn_g, tn_b, B0, st2);
    // S4: m = LN_cn(cpre) @ pm_W^T + pm_b                 (B0 -> B1)
    stage3_k<0, 1><<<768, 256, 0, stream>>>(B0, pmT, pm_b, st2, cn_g, cn_b, B1, nullptr);
    // S5: eopre = m @ Wmoe^T + b_moe ; stats -> st3       (B1 -> B0)
    stage3_k<2, 0><<<768, 256, 0, stream>>>(B1, WmoeT, b_moe, nullptr, nullptr, nullptr,
                                            B0, st3);
    // S6: out = relu(LN_mn(eopre)) @ out_W^T + out_b      (B0 -> d_out)
    stage3_k<0, 2><<<768, 256, 0, stream>>>(B0, outT, out_b, st3, mn_g, mn_b,
                                            (float*)d_out, nullptr);
}

// Round 4
// 538.314 us; speedup vs baseline: 1.9042x; 1.0390x over previous
//
#include <hip/hip_runtime.h>

#define DD 192

// =======================================================================
// stage3_k: C[s,i] = sum_j A'[s,j] * W[i,j] + bias[i]
//   A' = A (LNL=0), LN(A) (LNL=1), relu(LN(A)) (LNL=2)
//   LN stats come from stats_in[3][8192] (3 colgroup banks, summed here).
//   EMIT: 0 none, 1 partial colsum (emit[(b/3)*192 + c0+t] = sum_s C[s,i],
//         non-atomic), 2 stats (emit[cg*8192+2r]=rowsum,+1=rowsumsq).
// Block: 256 thr = 8 tr x 32 tc; tile 32 rows x 64 cols; thread = 4r x 2c.
// Grid: 384 = 3 colgroups x 128 rowgroups.  (proven R1 structure)
// =======================================================================
template <int EMIT, int LNL>
__global__ __launch_bounds__(256) void stage3_k(
    const float* __restrict__ A, const float* __restrict__ W,
    const float* __restrict__ bias,
    const float* __restrict__ stats_in, const float* __restrict__ lng,
    const float* __restrict__ lnb,
    float* __restrict__ out, float* __restrict__ emit_buf) {
    __shared__ float At[32 * 200];   // row-major, stride 200 (bank-stride 8)
    __shared__ float WT[DD * 64];    // swizzled: word j*64 + ((ip + 2*(j&31)) & 63)
    __shared__ float ms[32], rs[32];
    __shared__ float csum[4 * 64];

    const int t = threadIdx.x;
    const int tr = t >> 5, tc = t & 31;
    const int b = blockIdx.x;
    const int cg = b % 3;
    const int c0 = cg * 64;
    const int r0 = (b / 3) * 32;

    if (LNL > 0) {
        if (t < 32) {
            int r = r0 + t;
            float s = stats_in[2 * r] + stats_in[8192 + 2 * r] + stats_in[16384 + 2 * r];
            float q = stats_in[2 * r + 1] + stats_in[8192 + 2 * r + 1]
                    + stats_in[16384 + 2 * r + 1];
            float mean = s * (1.f / 192.f);
            float var = q * (1.f / 192.f) - mean * mean;
            ms[t] = mean;
            rs[t] = rsqrtf(var + 1e-5f);
        }
        __syncthreads();
    }

    // ---- stage A tile (32 x 192), applying LN(+ReLU) on load ----
    {
        const float4* A4 = (const float4*)(A + (size_t)r0 * DD);
#pragma unroll
        for (int q = 0; q < 6; q++) {
            int f = t + 256 * q;               // < 1536
            int r = f / 48, jj = f - r * 48;
            float4 v = A4[f];
            if (LNL > 0) {
                float mean = ms[r], rstd = rs[r];
                float4 g4 = ((const float4*)lng)[jj];
                float4 b4 = ((const float4*)lnb)[jj];
                v.x = (v.x - mean) * rstd * g4.x + b4.x;
                v.y = (v.y - mean) * rstd * g4.y + b4.y;
                v.z = (v.z - mean) * rstd * g4.z + b4.z;
                v.w = (v.w - mean) * rstd * g4.w + b4.w;
                if (LNL == 2) {
                    v.x = fmaxf(v.x, 0.f); v.y = fmaxf(v.y, 0.f);
                    v.z = fmaxf(v.z, 0.f); v.w = fmaxf(v.w, 0.f);
                }
            }
            *(float4*)&At[r * 200 + 4 * jj] = v;
        }
    }
    // ---- stage W slice (64 x 192) transposed+swizzled ----
    {
        const float4* W4 = (const float4*)(W + (size_t)c0 * DD);
#pragma unroll
        for (int q = 0; q < 12; q++) {
            int f = t + 256 * q;               // < 3072
            int ip = f / 48, jj = f - ip * 48;
            float4 v = W4[f];
            int j0 = 4 * jj;
            WT[(j0 + 0) * 64 + ((ip + 2 * ((j0 + 0) & 31)) & 63)] = v.x;
            WT[(j0 + 1) * 64 + ((ip + 2 * ((j0 + 1) & 31)) & 63)] = v.y;
            WT[(j0 + 2) * 64 + ((ip + 2 * ((j0 + 2) & 31)) & 63)] = v.z;
            WT[(j0 + 3) * 64 + ((ip + 2 * ((j0 + 3) & 31)) & 63)] = v.w;
        }
    }

    const int i0 = c0 + 2 * tc;
    float bv0 = bias[i0], bv1 = bias[i0 + 1];
    float acc[4][2];
#pragma unroll
    for (int i = 0; i < 4; i++) { acc[i][0] = bv0; acc[i][1] = bv1; }
    __syncthreads();

    const int rbase = 4 * tr;
#pragma unroll 2
    for (int jc = 0; jc < DD; jc += 8) {
        float a_[4][8];
#pragma unroll
        for (int rr = 0; rr < 4; rr++) {
            float4 u = *(const float4*)&At[(rbase + rr) * 200 + jc];
            float4 v = *(const float4*)&At[(rbase + rr) * 200 + jc + 4];
            a_[rr][0] = u.x; a_[rr][1] = u.y; a_[rr][2] = u.z; a_[rr][3] = u.w;
            a_[rr][4] = v.x; a_[rr][5] = v.y; a_[rr][6] = v.z; a_[rr][7] = v.w;
        }
#pragma unroll
        for (int jj = 0; jj < 8; jj++) {
            const int j = jc + jj;
            int cs = (2 * tc + 2 * (j & 31)) & 63;
            float2 w2 = *(const float2*)&WT[j * 64 + cs];
            acc[0][0] = fmaf(a_[0][jj], w2.x, acc[0][0]);
            acc[0][1] = fmaf(a_[0][jj], w2.y, acc[0][1]);
            acc[1][0] = fmaf(a_[1][jj], w2.x, acc[1][0]);
            acc[1][1] = fmaf(a_[1][jj], w2.y, acc[1][1]);
            acc[2][0] = fmaf(a_[2][jj], w2.x, acc[2][0]);
            acc[2][1] = fmaf(a_[2][jj], w2.y, acc[2][1]);
            acc[3][0] = fmaf(a_[3][jj], w2.x, acc[3][0]);
            acc[3][1] = fmaf(a_[3][jj], w2.y, acc[3][1]);
        }
    }

#pragma unroll
    for (int i = 0; i < 4; i++) {
        int row = r0 + rbase + i;
        *(float2*)&out[(size_t)row * DD + i0] = make_float2(acc[i][0], acc[i][1]);
    }

    if (EMIT == 2) {
#pragma unroll
        for (int i = 0; i < 4; i++) {
            float s = acc[i][0] + acc[i][1];
            float q = acc[i][0] * acc[i][0] + acc[i][1] * acc[i][1];
#pragma unroll
            for (int m = 16; m >= 1; m >>= 1) {
                s += __shfl_xor(s, m);
                q += __shfl_xor(q, m);
            }
            if (tc == 0) {
                int r = r0 + rbase + i;
                emit_buf[cg * 8192 + 2 * r] = s;
                emit_buf[cg * 8192 + 2 * r + 1] = q;
            }
        }
    } else if (EMIT == 1) {
        float cs0 = acc[0][0] + acc[1][0] + acc[2][0] + acc[3][0];
        float cs1 = acc[0][1] + acc[1][1] + acc[2][1] + acc[3][1];
        cs0 += __shfl_xor(cs0, 32);   // fold tr-pair within wave
        cs1 += __shfl_xor(cs1, 32);
        int w = t >> 6;
        if ((t & 63) < 32) {
            csum[w * 64 + 2 * tc] = cs0;
            csum[w * 64 + 2 * tc + 1] = cs1;
        }
        __syncthreads();
        if (t < 64) {
            float s = csum[t] + csum[64 + t] + csum[128 + t] + csum[192 + t];
            emit_buf[(size_t)(b / 3) * DD + c0 + t] = s;   // non-atomic partial
        }
    }
}

// =======================================================================
// feat2_k: a_pre[i] = sum_j xm[j]*(feat_W[i*192+j]+feat_AW[i*192+j,:]@xm
//                                  +feat_Ab[i*192+j])
// Grid 192 (one output i per block). xm computed in-block from s1's
// 128x192 partial colsums (no atomics). AW streamed global->reg (single
// use: no LDS staging). 8 lanes per AW row.
// =======================================================================
__global__ __launch_bounds__(256) void feat2_k(
    const float* __restrict__ feat_W, const float* __restrict__ feat_AW,
    const float* __restrict__ feat_Ab, const float* __restrict__ part,
    float* __restrict__ a_pre) {
    __shared__ float xms[DD];
    __shared__ float wsum[4];
    const int t = threadIdx.x;
    const int i = blockIdx.x;
    if (t < DD) {
        float s = 0.f;
        for (int rg = 0; rg < 128; rg++) s += part[rg * DD + t];
        xms[t] = s * (1.f / 4096.f);
    }
    __syncthreads();
    const int p = t & 7, rsub = t >> 3;   // 8 lanes/row, 32 rows/pass
    float xsl[24];
#pragma unroll
    for (int q = 0; q < 6; q++) {
        float4 v = *(const float4*)&xms[p * 4 + 32 * q];
        xsl[4*q] = v.x; xsl[4*q+1] = v.y; xsl[4*q+2] = v.z; xsl[4*q+3] = v.w;
    }
    float bacc = 0.f;
    for (int pass = 0; pass < 6; pass++) {
        int j = pass * 32 + rsub;                 // 0..191
        size_t k = (size_t)i * DD + j;
        const float4* row4 = (const float4*)(feat_AW + k * DD);
        float acc = 0.f;
#pragma unroll
        for (int q = 0; q < 6; q++) {
            float4 w = row4[p + 8 * q];
            acc = fmaf(w.x, xsl[4*q], acc);   acc = fmaf(w.y, xsl[4*q+1], acc);
            acc = fmaf(w.z, xsl[4*q+2], acc); acc = fmaf(w.w, xsl[4*q+3], acc);
        }
        acc += __shfl_xor(acc, 1);
        acc += __shfl_xor(acc, 2);
        acc += __shfl_xor(acc, 4);
        if (p == 0) bacc = fmaf(acc + feat_W[k] + feat_Ab[k], xms[j], bacc);
    }
    bacc += __shfl_xor(bacc, 8);
    bacc += __shfl_xor(bacc, 16);
    bacc += __shfl_xor(bacc, 32);
    if ((t & 63) == 0) wsum[t >> 6] = bacc;
    __syncthreads();
    if (t == 0) a_pre[i] = wsum[0] + wsum[1] + wsum[2] + wsum[3];
}

// =======================================================================
// vec_k: a0 = LN(a_pre + feat_b); gate = softmax(a0@gate_W^T + gate_b);
//        b_moe = sum_e gate[e]*ex_b[e,:]
// =======================================================================
__global__ __launch_bounds__(192) void vec_k(
    const float* __restrict__ a_pre, const float* __restrict__ feat_b,
    const float* __restrict__ an_g, const float* __restrict__ an_b,
    const float* __restrict__ gate_W, const float* __restrict__ gate_b,
    const float* __restrict__ ex_b, float* __restrict__ a0g,
    float* __restrict__ gateg, float* __restrict__ b_moe) {
    __shared__ float red[6];
    __shared__ float gred[24];
    __shared__ float lgs[8];
    const int t = threadIdx.x;
    const int w = t >> 6;
    float v = a_pre[t] + feat_b[t];
    float s = v, q = v * v;
#pragma unroll
    for (int m = 32; m >= 1; m >>= 1) { s += __shfl_xor(s, m); q += __shfl_xor(q, m); }
    if ((t & 63) == 0) { red[w] = s; red[3 + w] = q; }
    __syncthreads();
    float S = red[0] + red[1] + red[2];
    float Q = red[3] + red[4] + red[5];
    float mean = S * (1.f / 192.f);
    float var = Q * (1.f / 192.f) - mean * mean;
    float rstd = rsqrtf(var + 1e-5f);
    float a0v = (v - mean) * rstd * an_g[t] + an_b[t];
    a0g[t] = a0v;
#pragma unroll
    for (int e = 0; e < 8; e++) {
        float x = a0v * gate_W[e * DD + t];
#pragma unroll
        for (int m = 32; m >= 1; m >>= 1) x += __shfl_xor(x, m);
        if ((t & 63) == 0) gred[w * 8 + e] = x;
    }
    __syncthreads();
    if (t < 8) lgs[t] = gred[t] + gred[8 + t] + gred[16 + t] + gate_b[t];
    __syncthreads();
    if (t == 0) {
        float mx = lgs[0];
        for (int e = 1; e < 8; e++) mx = fmaxf(mx, lgs[e]);
        float sum = 0.f, ex[8];
        for (int e = 0; e < 8; e++) { ex[e] = expf(lgs[e] - mx); sum += ex[e]; }
        for (int e = 0; e < 8; e++) lgs[e] = ex[e] / sum;
    }
    __syncthreads();
    if (t < 8) gateg[t] = lgs[t];
    float bm = 0.f;
#pragma unroll
    for (int e = 0; e < 8; e++) bm = fmaf(lgs[e], ex_b[e * DD + t], bm);
    b_moe[t] = bm;
}

// =======================================================================
// hyper_k: streaming hypernet weights, global->reg (no LDS, no barriers,
// no atomics). 8 lanes per AW row, 32 rows per block. a0 slice kept in
// registers. Grid 3456: b<1152 MoE chunks FIRST (8 experts serially with
// expert-prefetch pipeline, gate-weighted sum, one non-atomic write),
// then 1152 Wt + 1152 Wc blocks fill the schedule tail.
// =======================================================================
__global__ __launch_bounds__(256) void hyper_k(
    const float* __restrict__ tm_W, const float* __restrict__ tm_AW,
    const float* __restrict__ tm_Ab, const float* __restrict__ cm_W,
    const float* __restrict__ cm_AW, const float* __restrict__ cm_Ab,
    const float* __restrict__ ex_W, const float* __restrict__ ex_AW,
    const float* __restrict__ ex_Ab, const float* __restrict__ a0g,
    const float* __restrict__ gateg, float* __restrict__ Wt,
    float* __restrict__ Wc, float* __restrict__ Wmoe) {
    const int t = threadIdx.x, b = blockIdx.x;
    const int p = t & 7, rsub = t >> 3;
    float asl[24];
#pragma unroll
    for (int q = 0; q < 6; q++) {
        float4 v = *(const float4*)&a0g[p * 4 + 32 * q];
        asl[4*q] = v.x; asl[4*q+1] = v.y; asl[4*q+2] = v.z; asl[4*q+3] = v.w;
    }
    if (b < 1152) {                        // MoE chunk, all 8 experts
        const int kk = b * 32 + rsub;      // < 36864
        float gv[8];
#pragma unroll
        for (int e = 0; e < 8; e++) gv[e] = gateg[e];
        float4 wv[6], wn[6];
        {
            const float4* row4 = (const float4*)(ex_AW + (size_t)kk * DD);
#pragma unroll
            for (int q = 0; q < 6; q++) wv[q] = row4[p + 8 * q];
        }
        float macc = 0.f;
#pragma unroll
        for (int e = 0; e < 8; e++) {
            if (e < 7) {
                const float4* nr =
                    (const float4*)(ex_AW + ((size_t)(e + 1) * 36864 + kk) * DD);
#pragma unroll
                for (int q = 0; q < 6; q++) wn[q] = nr[p + 8 * q];
            }
            float acc = 0.f;
#pragma unroll
            for (int q = 0; q < 6; q++) {
                acc = fmaf(wv[q].x, asl[4*q], acc);
                acc = fmaf(wv[q].y, asl[4*q+1], acc);
                acc = fmaf(wv[q].z, asl[4*q+2], acc);
                acc = fmaf(wv[q].w, asl[4*q+3], acc);
            }
            acc += __shfl_xor(acc, 1);
            acc += __shfl_xor(acc, 2);
            acc += __shfl_xor(acc, 4);
            macc = fmaf(gv[e],
                        acc + ex_W[(size_t)e * 36864 + kk] + ex_Ab[(size_t)e * 36864 + kk],
                        macc);
#pragma unroll
            for (int q = 0; q < 6; q++) wv[q] = wn[q];
        }
        if (p == 0) Wmoe[kk] = macc;
    } else {
        const bool isT = b < 2304;
        const int kk = (isT ? b - 1152 : b - 2304) * 32 + rsub;
        const float* AW = isT ? tm_AW : cm_AW;
        const float* WB = isT ? tm_W : cm_W;
        const float* AB = isT ? tm_Ab : cm_Ab;
        float* dst = isT ? Wt : Wc;
        const float4* row4 = (const float4*)(AW + (size_t)kk * DD);
        float acc = 0.f;
#pragma unroll
        for (int q = 0; q < 6; q++) {
            float4 w = row4[p + 8 * q];
            acc = fmaf(w.x, asl[4*q], acc);   acc = fmaf(w.y, asl[4*q+1], acc);
            acc = fmaf(w.z, asl[4*q+2], acc); acc = fmaf(w.w, asl[4*q+3], acc);
        }
        acc += __shfl_xor(acc, 1);
        acc += __shfl_xor(acc, 2);
        acc += __shfl_xor(acc, 4);
        if (p == 0) dst[kk] = acc + WB[kk] + AB[kk];
    }
}

// =======================================================================
extern "C" void kernel_launch(void* const* d_in, const int* in_sizes, int n_in,
                              void* d_out, int out_size, void* d_ws, size_t ws_size,
                              hipStream_t stream) {
    (void)in_sizes; (void)n_in; (void)out_size; (void)ws_size;
    const float* x       = (const float*)d_in[0];
    const float* W_in    = (const float*)d_in[1];
    const float* b_in    = (const float*)d_in[2];
    const float* feat_W  = (const float*)d_in[3];
    const float* feat_b  = (const float*)d_in[4];
    const float* feat_AW = (const float*)d_in[5];
    const float* feat_Ab = (const float*)d_in[6];
    const float* an_g    = (const float*)d_in[7];
    const float* an_b    = (const float*)d_in[8];
    const float* tm_W    = (const float*)d_in[9];
    const float* tm_b    = (const float*)d_in[10];
    const float* tm_AW   = (const float*)d_in[11];
    const float* tm_Ab   = (const float*)d_in[12];
    const float* tn_g    = (const float*)d_in[13];
    const float* tn_b    = (const float*)d_in[14];
    const float* cm_W    = (const float*)d_in[15];
    const float* cm_b    = (const float*)d_in[16];
    const float* cm_AW   = (const float*)d_in[17];
    const float* cm_Ab   = (const float*)d_in[18];
    const float* cn_g    = (const float*)d_in[19];
    const float* cn_b    = (const float*)d_in[20];
    const float* pm_W    = (const float*)d_in[21];
    const float* pm_b    = (const float*)d_in[22];
    const float* gate_W  = (const float*)d_in[23];
    const float* gate_b  = (const float*)d_in[24];
    const float* ex_W    = (const float*)d_in[25];
    const float* ex_b    = (const float*)d_in[26];
    const float* ex_AW   = (const float*)d_in[27];
    const float* ex_Ab   = (const float*)d_in[28];
    const float* mn_g    = (const float*)d_in[29];
    const float* mn_b    = (const float*)d_in[30];
    const float* out_W   = (const float*)d_in[31];
    const float* out_b   = (const float*)d_in[32];

    float* ws = (float*)d_ws;
    float* B0     = ws;                 // 786432
    float* B1     = ws + 786432;        // 786432
    float* part   = ws + 1572864;       // 24576 (128 rowgroups x 192, fully written)
    float* Wmoe   = ws + 1597440;       // 36864 (fully written, no atomics)
    float* Wt     = ws + 1634304;       // 36864
    float* Wc     = ws + 1671168;       // 36864
    float* st1    = ws + 1708032;       // 3*8192 (fully written)
    float* st2    = ws + 1732608;       // 3*8192
    float* st3    = ws + 1757184;       // 3*8192
    float* a_pre  = ws + 1781760;       // 192 (fully written, no atomics)
    float* a0     = ws + 1781952;       // 192
    float* gate   = ws + 1782144;       // 8
    float* b_moe  = ws + 1782152;       // 192

    // No memset needed: every buffer is fully written before it is read.

    // S1: h = x @ W_in^T + b_in ; partial colsums -> part  (x -> B0)
    stage3_k<1, 0><<<384, 256, 0, stream>>>(x, W_in, b_in, nullptr, nullptr, nullptr,
                                            B0, part);
    feat2_k<<<192, 256, 0, stream>>>(feat_W, feat_AW, feat_Ab, part, a_pre);
    vec_k<<<1, 192, 0, stream>>>(a_pre, feat_b, an_g, an_b, gate_W, gate_b, ex_b,
                                 a0, gate, b_moe);
    hyper_k<<<3456, 256, 0, stream>>>(tm_W, tm_AW, tm_Ab, cm_W, cm_AW, cm_Ab,
                                      ex_W, ex_AW, ex_Ab, a0, gate, Wt, Wc, Wmoe);
    // S2: tpre = h @ Wt^T + tm_b ; stats -> st1           (B0 -> B1)
    stage3_k<2, 0><<<384, 256, 0, stream>>>(B0, Wt, tm_b, nullptr, nullptr, nullptr,
                                            B1, st1);
    // S3: cpre = LN_tn(tpre) @ Wc^T + cm_b ; stats -> st2 (B1 -> B0)
    stage3_k<2, 1><<<384, 256, 0, stream>>>(B1, Wc, cm_b, st1, tn_g, tn_b, B0, st2);
    // S4: m = LN_cn(cpre) @ pm_W^T + pm_b                 (B0 -> B1)
    stage3_k<0, 1><<<384, 256, 0, stream>>>(B0, pm_W, pm_b, st2, cn_g, cn_b, B1, nullptr);
    // S5: eopre = m @ Wmoe^T + b_moe ; stats -> st3       (B1 -> B0)
    stage3_k<2, 0><<<384, 256, 0, stream>>>(B1, Wmoe, b_moe, nullptr, nullptr, nullptr,
                                            B0, st3);
    // S6: out = relu(LN_mn(eopre)) @ out_W^T + out_b      (B0 -> d_out)
    stage3_k<0, 2><<<384, 256, 0, stream>>>(B0, out_W, out_b, st3, mn_g, mn_b,
                                            (float*)d_out, nullptr);
}